// Round 16
// baseline (175.136 us; speedup 1.0000x reference)
//
#include <hip/hip_runtime.h>
#include <hip/hip_bf16.h>

typedef __attribute__((ext_vector_type(8))) short short8v;
typedef __attribute__((ext_vector_type(4))) float f32x4;

#define N_EDGES 1000000
#define NROWS   (N_EDGES * 3)
#define NTILES  (NROWS / 16)     // 187500 16-row tiles
#define NPAIRS  (NTILES / 2)     // 93750 pairs of adjacent tiles
#define XN_ELEMS (50000 * 3 * 32)

__device__ __forceinline__ unsigned short f2bf(float f) {
    unsigned u = __builtin_bit_cast(unsigned, f);
    u += 0x7fffu + ((u >> 16) & 1u);           // round-to-nearest-even
    return (unsigned short)(u >> 16);
}

// Mc rows 0..31: 0.5*M1+0.25*M2 (src part); rows 32..63: -0.5*M1+0.25*M2 (dst)
__global__ void build_mc(const float* __restrict__ M1, const float* __restrict__ M2,
                         unsigned short* __restrict__ mc) {
    int i = blockIdx.x * blockDim.x + threadIdx.x;
    if (i >= 64 * 32) return;
    int k = i >> 5;
    int f = i & 31;
    float v;
    if (k < 32) v =  0.5f * M1[k * 32 + f]        + 0.25f * M2[k * 32 + f];
    else        v = -0.5f * M1[(k - 32) * 32 + f] + 0.25f * M2[(k - 32) * 32 + f];
    mc[i] = f2bf(v);
}

typedef __attribute__((ext_vector_type(4))) unsigned short u16x4;

__global__ __launch_bounds__(256) void convert_xn(const float* __restrict__ xn,
                                                  unsigned short* __restrict__ xb) {
    const int n4 = XN_ELEMS / 4;
    int i = blockIdx.x * blockDim.x + threadIdx.x;
    const int stride = gridDim.x * blockDim.x;
    for (; i < n4; i += stride) {
        f32x4 v = __builtin_nontemporal_load((const f32x4*)xn + i);
        u16x4 o;
        o[0] = f2bf(v.x); o[1] = f2bf(v.y); o[2] = f2bf(v.z); o[3] = f2bf(v.w);
        *((u16x4*)xb + i) = o;
    }
}

struct G4 { f32x4 w0, w1; short8v xs, xt; };

__global__ __launch_bounds__(256, 2) void n2e_main(
    const unsigned short* __restrict__ xb,   // bf16 xn copy (ws)
    const int*   __restrict__ src_idx,
    const int*   __restrict__ dst_idx,
    const float* __restrict__ W,
    const unsigned short* __restrict__ mc,
    float* __restrict__ out)
{
    __shared__ char lds[4][4096];            // per-wave 4KB pair-staging buffer

    const int lane = threadIdx.x & 63;
    const int wid  = threadIdx.x >> 6;
    const int col  = lane & 15;        // edge-row within tile / D col
    const int kg   = lane >> 4;        // 0..3
    const int kk   = kg << 3;          // k-offset of this lane's 8 elements

    // Mc^T fragments (MFMA A operand): lane holds Mc[k=kk+i][half*16+col]
    short8v B00, B01, B10, B11;
    #pragma unroll
    for (int i = 0; i < 8; ++i) {
        int k0 = (kk + i) * 32;
        int k1 = (32 + kk + i) * 32;
        B00[i] = (short)mc[k0 + col];
        B01[i] = (short)mc[k0 + 16 + col];
        B10[i] = (short)mc[k1 + col];
        B11[i] = (short)mc[k1 + 16 + col];
    }

    // CHUNKED mapping: wave owns a CONTIGUOUS run of pairs -> its write
    // stream is sequential across iterations (fill-like), unlike grid-stride
    // whose 4KB windows jump NW*4KB per iteration. Single lever vs R14.
    const int NW = gridDim.x * 4;
    const int gw = blockIdx.x * 4 + wid;
    const int q  = NPAIRS / NW;
    const int rr = NPAIRS % NW;
    int p0, cnt;
    if (gw < rr) { cnt = q + 1; p0 = gw * cnt; }
    else         { cnt = q;     p0 = rr * (q + 1) + (gw - rr) * q; }
    if (cnt <= 0) return;
    const int plastP = p0 + cnt - 1;

    auto pairP = [&](int j) -> int {
        int P = p0 + j;
        return (P <= plastP) ? P : plastP;
    };
    auto erow = [&](int T, int& e, int& d) {
        int row = (T << 4) + col;
        e = (int)((unsigned)row / 3u);
        d = row - e * 3;
    };
    auto ld_idx = [&](int T, int& s, int& t) {
        int e, d; erow(T, e, d);
        s = src_idx[e];
        t = dst_idx[e];
    };
    auto gather = [&](int T, int s, int t) -> G4 {
        int e, d; erow(T, e, d);
        G4 g;
        const float* wp = W + (size_t)e * 32 + kk;
        g.w0 = *(const f32x4*)wp;
        g.w1 = *(const f32x4*)(wp + 4);
        g.xs = *(const short8v*)(xb + ((size_t)s * 3 + d) * 32 + kk);
        g.xt = *(const short8v*)(xb + ((size_t)t * 3 + d) * 32 + kk);
        return g;
    };

    // ---- prologue: pairs 0,1 gathered; idx queue for pairs 2,3 ----
    int s0A, t0A, s1A, t1A, s0B, t0B, s1B, t1B;
    ld_idx(pairP(0) * 2,     s0A, t0A);
    ld_idx(pairP(0) * 2 + 1, s1A, t1A);
    ld_idx(pairP(1) * 2,     s0B, t0B);
    ld_idx(pairP(1) * 2 + 1, s1B, t1B);
    G4 gA0 = gather(pairP(0) * 2,     s0A, t0A);
    G4 gA1 = gather(pairP(0) * 2 + 1, s1A, t1A);
    G4 gB0 = gather(pairP(1) * 2,     s0B, t0B);
    G4 gB1 = gather(pairP(1) * 2 + 1, s1B, t1B);

    int sQ0a, tQ0a, sQ0b, tQ0b, sQ1a, tQ1a, sQ1b, tQ1b;
    ld_idx(pairP(2) * 2,     sQ0a, tQ0a);
    ld_idx(pairP(2) * 2 + 1, sQ0b, tQ0b);
    ld_idx(pairP(3) * 2,     sQ1a, tQ1a);
    ld_idx(pairP(3) * 2 + 1, sQ1b, tQ1b);

    // per-lane constant read-side unswizzle (row&7 is invariant across i)
    const int rxor = ((lane >> 3) & 7) << 4;

    for (int j = 0; j < cnt; ++j) {
        const int pc = p0 + j;

        // ---- prefetch-issue section (pinned before compute) ----
        G4 gC0 = gather(pairP(j + 2) * 2,     sQ0a, tQ0a);
        G4 gC1 = gather(pairP(j + 2) * 2 + 1, sQ0b, tQ0b);

        int sNa, tNa, sNb, tNb;
        ld_idx(pairP(j + 4) * 2,     sNa, tNa);
        ld_idx(pairP(j + 4) * 2 + 1, sNb, tNb);

        __builtin_amdgcn_sched_barrier(0);

        // ---- compute the two tiles of current pair into LDS ----
        #pragma unroll
        for (int h = 0; h < 2; ++h) {
            const G4& g = h ? gA1 : gA0;

            float xsf[8], xtf[8];
            #pragma unroll
            for (int i = 0; i < 8; ++i) {
                xsf[i] = __builtin_bit_cast(float, ((unsigned)(unsigned short)g.xs[i]) << 16);
                xtf[i] = __builtin_bit_cast(float, ((unsigned)(unsigned short)g.xt[i]) << 16);
            }
            union { short8v v; __hip_bfloat162 h2[4]; } ua, ub;
            ua.h2[0] = __float22bfloat162_rn(make_float2(g.w0.x * xsf[0], g.w0.y * xsf[1]));
            ua.h2[1] = __float22bfloat162_rn(make_float2(g.w0.z * xsf[2], g.w0.w * xsf[3]));
            ua.h2[2] = __float22bfloat162_rn(make_float2(g.w1.x * xsf[4], g.w1.y * xsf[5]));
            ua.h2[3] = __float22bfloat162_rn(make_float2(g.w1.z * xsf[6], g.w1.w * xsf[7]));
            ub.h2[0] = __float22bfloat162_rn(make_float2(g.w0.x * xtf[0], g.w0.y * xtf[1]));
            ub.h2[1] = __float22bfloat162_rn(make_float2(g.w0.z * xtf[2], g.w0.w * xtf[3]));
            ub.h2[2] = __float22bfloat162_rn(make_float2(g.w1.x * xtf[4], g.w1.y * xtf[5]));
            ub.h2[3] = __float22bfloat162_rn(make_float2(g.w1.z * xtf[6], g.w1.w * xtf[7]));

            f32x4 acc0 = {0.f, 0.f, 0.f, 0.f};   // f = kg*4+i
            f32x4 acc1 = {0.f, 0.f, 0.f, 0.f};   // f = kg*4+i + 16
            acc0 = __builtin_amdgcn_mfma_f32_16x16x32_bf16(B00, ua.v, acc0, 0, 0, 0);
            acc0 = __builtin_amdgcn_mfma_f32_16x16x32_bf16(B10, ub.v, acc0, 0, 0, 0);
            acc1 = __builtin_amdgcn_mfma_f32_16x16x32_bf16(B01, ua.v, acc1, 0, 0, 0);
            acc1 = __builtin_amdgcn_mfma_f32_16x16x32_bf16(B11, ub.v, acc1, 0, 0, 0);

            // stage to LDS, xor-swizzled by row (=col) to dodge bank conflicts
            char* base = &lds[wid][h * 2048];
            const int wb = col * 128 + kg * 16;
            const int wx = (col & 7) << 4;
            *(f32x4*)(base + ((wb)      ^ wx)) = acc0;
            *(f32x4*)(base + ((wb + 64) ^ wx)) = acc1;
        }

        // ---- contiguous epilogue: 4x 1KB wave-contiguous stores ----
        {
            char* base = &lds[wid][0];
            char* opb  = (char*)(out + (size_t)pc * 1024);
            #pragma unroll
            for (int i = 0; i < 4; ++i) {
                f32x4 v = *(const f32x4*)(base + ((lane * 16 + i * 1024) ^ rxor));
                *(f32x4*)(opb + lane * 16 + i * 1024) = v;
            }
        }

        // rotate pipeline registers
        gA0 = gB0; gA1 = gB1;
        gB0 = gC0; gB1 = gC1;
        sQ0a = sQ1a; tQ0a = tQ1a; sQ0b = sQ1b; tQ0b = tQ1b;
        sQ1a = sNa;  tQ1a = tNa;  sQ1b = sNb;  tQ1b = tNb;
    }
}

extern "C" void kernel_launch(void* const* d_in, const int* in_sizes, int n_in,
                              void* d_out, int out_size, void* d_ws, size_t ws_size,
                              hipStream_t stream) {
    const float* xn  = (const float*)d_in[0];
    const int*   xs  = (const int*)  d_in[1];
    const int*   xd  = (const int*)  d_in[2];
    const float* W   = (const float*)d_in[3];
    const float* M1  = (const float*)d_in[4];
    const float* M2  = (const float*)d_in[5];
    float* out = (float*)d_out;

    unsigned short* mc = (unsigned short*)d_ws;                 // 4 KB
    unsigned short* xb = (unsigned short*)((char*)d_ws + 4096); // 9.6 MB

    hipLaunchKernelGGL(build_mc, dim3(8), dim3(256), 0, stream, M1, M2, mc);
    hipLaunchKernelGGL(convert_xn, dim3(1024), dim3(256), 0, stream, xn, xb);
    hipLaunchKernelGGL(n2e_main, dim3(512), dim3(256), 0, stream,
                       xb, xs, xd, W, mc, out);
}

// Round 17
// 145.566 us; speedup vs baseline: 1.2031x; 1.2031x over previous
//
#include <hip/hip_runtime.h>
#include <hip/hip_bf16.h>

typedef __attribute__((ext_vector_type(8))) short short8v;
typedef __attribute__((ext_vector_type(4))) float f32x4;

#define N_EDGES 1000000
#define NROWS   (N_EDGES * 3)
#define NTILES  (NROWS / 16)     // 187500 16-row tiles
#define NPAIRS  (NTILES / 2)     // 93750 pairs of adjacent tiles
#define XN_ELEMS (50000 * 3 * 32)

__device__ __forceinline__ unsigned short f2bf(float f) {
    unsigned u = __builtin_bit_cast(unsigned, f);
    u += 0x7fffu + ((u >> 16) & 1u);           // round-to-nearest-even
    return (unsigned short)(u >> 16);
}

// Mc rows 0..31: 0.5*M1+0.25*M2 (src part); rows 32..63: -0.5*M1+0.25*M2 (dst)
__global__ void build_mc(const float* __restrict__ M1, const float* __restrict__ M2,
                         unsigned short* __restrict__ mc) {
    int i = blockIdx.x * blockDim.x + threadIdx.x;
    if (i >= 64 * 32) return;
    int k = i >> 5;
    int f = i & 31;
    float v;
    if (k < 32) v =  0.5f * M1[k * 32 + f]        + 0.25f * M2[k * 32 + f];
    else        v = -0.5f * M1[(k - 32) * 32 + f] + 0.25f * M2[(k - 32) * 32 + f];
    mc[i] = f2bf(v);
}

typedef __attribute__((ext_vector_type(4))) unsigned short u16x4;

__global__ __launch_bounds__(256) void convert_xn(const float* __restrict__ xn,
                                                  unsigned short* __restrict__ xb) {
    const int n4 = XN_ELEMS / 4;
    int i = blockIdx.x * blockDim.x + threadIdx.x;
    const int stride = gridDim.x * blockDim.x;
    for (; i < n4; i += stride) {
        f32x4 v = __builtin_nontemporal_load((const f32x4*)xn + i);
        u16x4 o;
        o[0] = f2bf(v.x); o[1] = f2bf(v.y); o[2] = f2bf(v.z); o[3] = f2bf(v.w);
        *((u16x4*)xb + i) = o;
    }
}

struct G4 { f32x4 w0, w1; short8v xs, xt; };

__global__ __launch_bounds__(256, 2) void n2e_main(
    const unsigned short* __restrict__ xb,   // bf16 xn copy (ws)
    const int*   __restrict__ src_idx,
    const int*   __restrict__ dst_idx,
    const float* __restrict__ W,
    const unsigned short* __restrict__ mc,
    float* __restrict__ out)
{
    __shared__ char lds[4][4096];            // per-wave 4KB pair-staging buffer

    const int lane = threadIdx.x & 63;
    const int wid  = threadIdx.x >> 6;
    const int col  = lane & 15;        // edge-row within tile / D col
    const int kg   = lane >> 4;        // 0..3
    const int kk   = kg << 3;          // k-offset of this lane's 8 elements

    // Mc^T fragments (MFMA A operand): lane holds Mc[k=kk+i][half*16+col]
    short8v B00, B01, B10, B11;
    #pragma unroll
    for (int i = 0; i < 8; ++i) {
        int k0 = (kk + i) * 32;
        int k1 = (32 + kk + i) * 32;
        B00[i] = (short)mc[k0 + col];
        B01[i] = (short)mc[k0 + 16 + col];
        B10[i] = (short)mc[k1 + col];
        B11[i] = (short)mc[k1 + 16 + col];
    }

    const int NW = gridDim.x * 4;
    const int gw = blockIdx.x * 4 + wid;
    if (gw >= NPAIRS) return;
    const int cnt = (NPAIRS - 1 - gw) / NW + 1;
    const int plastP = gw + (cnt - 1) * NW;

    auto pairP = [&](int j) -> int {
        long long P = (long long)gw + (long long)j * NW;
        return (P <= plastP) ? (int)P : plastP;
    };
    auto erow = [&](int T, int& e, int& d) {
        int row = (T << 4) + col;
        e = (int)((unsigned)row / 3u);
        d = row - e * 3;
    };
    auto ld_idx = [&](int T, int& s, int& t) {
        int e, d; erow(T, e, d);
        s = src_idx[e];
        t = dst_idx[e];
    };
    auto gather = [&](int T, int s, int t) -> G4 {
        int e, d; erow(T, e, d);
        G4 g;
        const float* wp = W + (size_t)e * 32 + kk;
        g.w0 = *(const f32x4*)wp;
        g.w1 = *(const f32x4*)(wp + 4);
        g.xs = *(const short8v*)(xb + ((size_t)s * 3 + d) * 32 + kk);
        g.xt = *(const short8v*)(xb + ((size_t)t * 3 + d) * 32 + kk);
        return g;
    };

    // ---- prologue: pairs 0,1 gathered; idx queue for pairs 2,3 ----
    int s0A, t0A, s1A, t1A, s0B, t0B, s1B, t1B;
    ld_idx(pairP(0) * 2,     s0A, t0A);
    ld_idx(pairP(0) * 2 + 1, s1A, t1A);
    ld_idx(pairP(1) * 2,     s0B, t0B);
    ld_idx(pairP(1) * 2 + 1, s1B, t1B);
    G4 gA0 = gather(pairP(0) * 2,     s0A, t0A);
    G4 gA1 = gather(pairP(0) * 2 + 1, s1A, t1A);
    G4 gB0 = gather(pairP(1) * 2,     s0B, t0B);
    G4 gB1 = gather(pairP(1) * 2 + 1, s1B, t1B);

    int sQ0a, tQ0a, sQ0b, tQ0b, sQ1a, tQ1a, sQ1b, tQ1b;
    ld_idx(pairP(2) * 2,     sQ0a, tQ0a);
    ld_idx(pairP(2) * 2 + 1, sQ0b, tQ0b);
    ld_idx(pairP(3) * 2,     sQ1a, tQ1a);
    ld_idx(pairP(3) * 2 + 1, sQ1b, tQ1b);

    // per-lane constant read-side unswizzle (row&7 is invariant across i)
    const int rxor = ((lane >> 3) & 7) << 4;

    for (int j = 0; j < cnt; ++j) {
        const int pc = gw + j * NW;

        // ---- prefetch-issue section (pinned before compute) ----
        G4 gC0 = gather(pairP(j + 2) * 2,     sQ0a, tQ0a);
        G4 gC1 = gather(pairP(j + 2) * 2 + 1, sQ0b, tQ0b);

        int sNa, tNa, sNb, tNb;
        ld_idx(pairP(j + 4) * 2,     sNa, tNa);
        ld_idx(pairP(j + 4) * 2 + 1, sNb, tNb);

        __builtin_amdgcn_sched_barrier(0);

        // ---- compute the two tiles of current pair into LDS ----
        #pragma unroll
        for (int h = 0; h < 2; ++h) {
            const G4& g = h ? gA1 : gA0;

            float xsf[8], xtf[8];
            #pragma unroll
            for (int i = 0; i < 8; ++i) {
                xsf[i] = __builtin_bit_cast(float, ((unsigned)(unsigned short)g.xs[i]) << 16);
                xtf[i] = __builtin_bit_cast(float, ((unsigned)(unsigned short)g.xt[i]) << 16);
            }
            union { short8v v; __hip_bfloat162 h2[4]; } ua, ub;
            ua.h2[0] = __float22bfloat162_rn(make_float2(g.w0.x * xsf[0], g.w0.y * xsf[1]));
            ua.h2[1] = __float22bfloat162_rn(make_float2(g.w0.z * xsf[2], g.w0.w * xsf[3]));
            ua.h2[2] = __float22bfloat162_rn(make_float2(g.w1.x * xsf[4], g.w1.y * xsf[5]));
            ua.h2[3] = __float22bfloat162_rn(make_float2(g.w1.z * xsf[6], g.w1.w * xsf[7]));
            ub.h2[0] = __float22bfloat162_rn(make_float2(g.w0.x * xtf[0], g.w0.y * xtf[1]));
            ub.h2[1] = __float22bfloat162_rn(make_float2(g.w0.z * xtf[2], g.w0.w * xtf[3]));
            ub.h2[2] = __float22bfloat162_rn(make_float2(g.w1.x * xtf[4], g.w1.y * xtf[5]));
            ub.h2[3] = __float22bfloat162_rn(make_float2(g.w1.z * xtf[6], g.w1.w * xtf[7]));

            f32x4 acc0 = {0.f, 0.f, 0.f, 0.f};   // f = kg*4+i
            f32x4 acc1 = {0.f, 0.f, 0.f, 0.f};   // f = kg*4+i + 16
            acc0 = __builtin_amdgcn_mfma_f32_16x16x32_bf16(B00, ua.v, acc0, 0, 0, 0);
            acc0 = __builtin_amdgcn_mfma_f32_16x16x32_bf16(B10, ub.v, acc0, 0, 0, 0);
            acc1 = __builtin_amdgcn_mfma_f32_16x16x32_bf16(B01, ua.v, acc1, 0, 0, 0);
            acc1 = __builtin_amdgcn_mfma_f32_16x16x32_bf16(B11, ub.v, acc1, 0, 0, 0);

            // stage to LDS, xor-swizzled by row (=col) to dodge bank conflicts
            char* base = &lds[wid][h * 2048];
            const int wb = col * 128 + kg * 16;
            const int wx = (col & 7) << 4;
            *(f32x4*)(base + ((wb)      ^ wx)) = acc0;
            *(f32x4*)(base + ((wb + 64) ^ wx)) = acc1;
        }

        // ---- contiguous epilogue: 4x 1KB wave-contiguous NT stores ----
        // Full-line nt stores bypass L2/L3 allocation: the 384MB out stream
        // stops thrashing the 256MB L3, keeping xb (9.6MB) + W L3-resident
        // for the gathers. (R5's nt regression was the 16B-scatter shape,
        // not nt itself.)
        {
            char* base = &lds[wid][0];
            char* opb  = (char*)(out + (size_t)pc * 1024);
            #pragma unroll
            for (int i = 0; i < 4; ++i) {
                f32x4 v = *(const f32x4*)(base + ((lane * 16 + i * 1024) ^ rxor));
                __builtin_nontemporal_store(v, (f32x4*)(opb + lane * 16 + i * 1024));
            }
        }

        // rotate pipeline registers
        gA0 = gB0; gA1 = gB1;
        gB0 = gC0; gB1 = gC1;
        sQ0a = sQ1a; tQ0a = tQ1a; sQ0b = sQ1b; tQ0b = tQ1b;
        sQ1a = sNa;  tQ1a = tNa;  sQ1b = sNb;  tQ1b = tNb;
    }
}

extern "C" void kernel_launch(void* const* d_in, const int* in_sizes, int n_in,
                              void* d_out, int out_size, void* d_ws, size_t ws_size,
                              hipStream_t stream) {
    const float* xn  = (const float*)d_in[0];
    const int*   xs  = (const int*)  d_in[1];
    const int*   xd  = (const int*)  d_in[2];
    const float* W   = (const float*)d_in[3];
    const float* M1  = (const float*)d_in[4];
    const float* M2  = (const float*)d_in[5];
    float* out = (float*)d_out;

    unsigned short* mc = (unsigned short*)d_ws;                 // 4 KB
    unsigned short* xb = (unsigned short*)((char*)d_ws + 4096); // 9.6 MB

    hipLaunchKernelGGL(build_mc, dim3(8), dim3(256), 0, stream, M1, M2, mc);
    hipLaunchKernelGGL(convert_xn, dim3(1024), dim3(256), 0, stream, xn, xb);
    hipLaunchKernelGGL(n2e_main, dim3(512), dim3(256), 0, stream,
                       xb, xs, xd, W, mc, out);
}